// Round 8
// baseline (1621.676 us; speedup 1.0000x reference)
//
#include <hip/hip_runtime.h>
#include <hip/hip_cooperative_groups.h>
#include <math.h>

#define BB 512
#define NN 16
#define CC 256
#define KK 8192
#define BNC (BB*NN*CC)

typedef unsigned char u8;
typedef unsigned long long u64;
typedef __attribute__((ext_vector_type(8))) int i32x8;
typedef __attribute__((ext_vector_type(4))) float f32x4;

#define SCALE_A 0x7D7D7D7D   // e8m0 125 -> 2^-2  (rest stored x4)
#define SCALE_B 0x73737373   // e8m0 115 -> 2^-12 (emb stored x4096)

namespace cg = cooperative_groups;

__device__ __forceinline__ void gl2lds16(const void* g, void* l) {
    __builtin_amdgcn_global_load_lds(
        (const __attribute__((address_space(1))) void*)g,
        (__attribute__((address_space(3))) void*)l, 16, 0, 0);
}
__device__ __forceinline__ u8 f2fp8(float x) {
    int r = __builtin_amdgcn_cvt_pk_fp8_f32(x, x, 0, false);
    return (u8)(r & 0xFF);
}
__device__ __forceinline__ u64 shfl_xor_u64(u64 v, int m) {
    unsigned lo = (unsigned)v, hi = (unsigned)(v >> 32);
    lo = __shfl_xor(lo, m, 64);
    hi = __shfl_xor(hi, m, 64);
    return ((u64)hi << 32) | lo;
}

// ---------------------------------------------------------------------------
// One persistent cooperative kernel: prologue (emb->fp8, init pool, packed init)
// -> 16x [dist (fp8 MX MFMA, barrier-free K-loop) | grid.sync | update/pool |
// grid.sync] -> final scalar reduce.
__global__ __launch_bounds__(256, 2) void vq_kernel(
        const float* __restrict__ f, const float* __restrict__ emb,
        float* __restrict__ f_rest, u8* __restrict__ rest8,
        u8* __restrict__ emb8, u64* __restrict__ packed_all,
        float* __restrict__ slots, float* __restrict__ out) {
    __shared__ __align__(16) u8 smem[81920];   // 16 KB A | 64 KB B-ring
    u8* sA = smem;
    u8* sB = smem + 16384;

    cg::grid_group grid = cg::this_grid();
    const int tid = threadIdx.x;
    const int bid = blockIdx.x;
    const int nb  = gridDim.x;
    const int w = tid >> 6, l = tid & 63;
    const int ccol = l & 15, quad = l >> 4;
    const int gtid = bid * 256 + tid;
    const int gstride = nb * 256;
    const int sg = ((l & 7) - (l >> 3)) & 7;   // B stage granule perm

    // ---------------- prologue ----------------
    for (int i = gtid; i < KK * CC / 4; i += gstride) {
        float4 v = ((const float4*)emb)[i];
        int p = __builtin_amdgcn_cvt_pk_fp8_f32(v.x*4096.f, v.y*4096.f, 0, false);
        p = __builtin_amdgcn_cvt_pk_fp8_f32(v.z*4096.f, v.w*4096.f, p, true);
        ((int*)emb8)[i] = p;
    }
    for (int b = bid; b < BB; b += nb) {
        const float* base = f + (size_t)b * NN * CC + tid;
        float a = 0.f;
        #pragma unroll
        for (int n = 0; n < NN; ++n) a += base[n * CC];
        rest8[(size_t)b * CC + tid] = f2fp8(a * 0.25f);   // mean/16 * 4
    }
    for (int i = gtid; i < BB * 136; i += gstride) packed_all[i] = ~0ull;
    if (gtid < 256) slots[gtid] = 0.f;
    grid.sync();

    for (int pn = 1; pn <= NN; ++pn) {
        u64* packed = packed_all + (size_t)BB * (pn * (pn - 1) / 2);
        // ================= dist phase =================
        const int splits = (pn <= 2) ? 32 : (pn <= 4) ? 16 : (pn <= 8) ? 8 : 4;
        const int cpb = KK / splits, ncb = cpb >> 8, nci = ncb * 2;
        const int rt = pn * 8, T = rt * splits;

        for (int t = bid; t < T; t += nb) {
            const int r0 = (t % rt) * 64;
            const int c0 = (t / rt) * cpb;
            // stage A: slot(r,g) = r*256B + ((g+r)&15)*16B  (granule-rotate)
            #pragma unroll
            for (int o = 0; o < 4; ++o) {
                int r = w * 16 + o * 4 + (l >> 4);
                int g = ((l & 15) - r) & 15;
                gl2lds16(rest8 + (size_t)(r0 + r) * CC + g * 16,
                         sA + (w * 16 + o * 4) * 256);
            }
            // stage chunks ci=0,1 (cb=0, ki=0/1): slot(c,g)=c*128B+((g+c)&7)*16B
            {
                const u8* b0 = emb8 + (size_t)(c0 + w * 64) * CC;
                #pragma unroll
                for (int o = 0; o < 8; ++o) {
                    int c = o * 8 + (l >> 3);
                    gl2lds16(b0 + (size_t)c * CC + sg * 16,
                             sB + w * 16384 + o * 1024);
                }
                #pragma unroll
                for (int o = 0; o < 8; ++o) {
                    int c = o * 8 + (l >> 3);
                    gl2lds16(b0 + (size_t)c * CC + 128 + sg * 16,
                             sB + w * 16384 + 8192 + o * 1024);
                }
            }
            __syncthreads();

            float best[16];
            #pragma unroll
            for (int q = 0; q < 16; ++q) best[q] = 1e30f;
            f32x4 acc[4][4];

            for (int ci = 0; ci < nci; ++ci) {
                const int cb = ci >> 1, ki = ci & 1;
                if (ci == nci - 1) __builtin_amdgcn_s_waitcnt(0x0F70); // vmcnt(0)
                else               __builtin_amdgcn_s_waitcnt(0x0F78); // vmcnt(8)

                const u8* wb = sB + w * 16384 + ki * 8192;
                i32x8 afr[4], bfr[4];
                #pragma unroll
                for (int tt = 0; tt < 4; ++tt) {
                    int r = tt * 16 + ccol;
                    int g0 = ki * 8 + quad * 2;
                    int4 lo = *(const int4*)(sA + r * 256 + ((g0 + r) & 15) * 16);
                    int4 hi = *(const int4*)(sA + r * 256 + ((g0 + 1 + r) & 15) * 16);
                    i32x8 v;
                    v[0]=lo.x; v[1]=lo.y; v[2]=lo.z; v[3]=lo.w;
                    v[4]=hi.x; v[5]=hi.y; v[6]=hi.z; v[7]=hi.w;
                    afr[tt] = v;
                }
                #pragma unroll
                for (int j = 0; j < 4; ++j) {
                    int c = j * 16 + ccol;
                    int g0 = quad * 2;
                    int4 lo = *(const int4*)(wb + c * 128 + ((g0 + c) & 7) * 16);
                    int4 hi = *(const int4*)(wb + c * 128 + ((g0 + 1 + c) & 7) * 16);
                    i32x8 v;
                    v[0]=lo.x; v[1]=lo.y; v[2]=lo.z; v[3]=lo.w;
                    v[4]=hi.x; v[5]=hi.y; v[6]=hi.z; v[7]=hi.w;
                    bfr[j] = v;
                }
                if (ki == 0) {
                    const f32x4 z = {0.f, 0.f, 0.f, 0.f};
                    #pragma unroll
                    for (int tt = 0; tt < 4; ++tt)
                        #pragma unroll
                        for (int j = 0; j < 4; ++j) acc[tt][j] = z;
                }
                #pragma unroll
                for (int tt = 0; tt < 4; ++tt)
                    #pragma unroll
                    for (int j = 0; j < 4; ++j)
                        acc[tt][j] = __builtin_amdgcn_mfma_scale_f32_16x16x128_f8f6f4(
                                        afr[tt], bfr[j], acc[tt][j],
                                        0, 0, 0, SCALE_A, 0, SCALE_B);
                // stage chunk ci+2 into slot (ci+2)&1 == ki
                if (ci + 2 < nci) {
                    const int cb2 = (ci + 2) >> 1, ki2 = (ci + 2) & 1;
                    const u8* b2 = emb8 + (size_t)(c0 + cb2 * 256 + w * 64) * CC
                                   + ki2 * 128;
                    #pragma unroll
                    for (int o = 0; o < 8; ++o) {
                        int c = o * 8 + (l >> 3);
                        gl2lds16(b2 + (size_t)c * CC + sg * 16,
                                 sB + w * 16384 + ki2 * 8192 + o * 1024);
                    }
                }
                if (ki == 1) {
                    // fold: maximize dot == minimize -dot; idx in low 7 mantissa
                    #pragma unroll
                    for (int tt = 0; tt < 4; ++tt)
                        #pragma unroll
                        for (int r = 0; r < 4; ++r) {
                            const int slot = tt * 4 + r;
                            #pragma unroll
                            for (int j = 0; j < 4; ++j) {
                                float nd = -acc[tt][j][r];
                                unsigned u_ = (__float_as_uint(nd) & 0xFFFFFF80u)
                                              | (unsigned)((cb << 2) | j);
                                best[slot] = fminf(best[slot], __uint_as_float(u_));
                            }
                        }
                }
            }
            // epilogue: merge 16 ccol-lanes per quad (they share rows)
            #pragma unroll
            for (int tt = 0; tt < 4; ++tt)
                #pragma unroll
                for (int r = 0; r < 4; ++r) {
                    unsigned u_ = __float_as_uint(best[tt * 4 + r]);
                    int idx = u_ & 0x7F;
                    int k = c0 + (idx >> 2) * 256 + w * 64 + (idx & 3) * 16 + ccol;
                    int sgn = ((int)u_) >> 31;
                    unsigned ordu = u_ ^ ((unsigned)sgn | 0x80000000u);
                    u64 p = ((u64)ordu << 32) | (unsigned)k;
                    #pragma unroll
                    for (int m = 1; m < 16; m <<= 1) {
                        u64 o = shfl_xor_u64(p, m);
                        if (o < p) p = o;
                    }
                    if (ccol == 0)
                        atomicMin(&packed[r0 + tt * 16 + quad * 4 + r], p);
                }
            __builtin_amdgcn_s_waitcnt(0x0F70);   // drain atomics + tail stages
            __syncthreads();
        }
        grid.sync();

        // ================= update phase =================
        int* sk = (int*)smem;
        float* red = (float*)(smem + 64);
        for (int b = bid; b < BB; b += nb) {
            __syncthreads();
            if (tid < pn)
                sk[tid] = (int)(unsigned)(packed[b * pn + tid] & 0xffffffffull);
            __syncthreads();
            float fr[NN];
            float acc_sq = 0.f;
            const int c = tid;
            #pragma unroll
            for (int n = 0; n < NN; ++n) {
                double pos = (n + 0.5) * ((double)pn / 16.0) - 0.5;
                if (pos < 0.0) pos = 0.0;
                int i0 = (int)floor(pos);
                if (i0 > pn - 1) i0 = pn - 1;
                int i1 = i0 + 1;
                if (i1 > pn - 1) i1 = pn - 1;
                double frac = pos - (double)i0;
                float w1 = (float)frac;
                float w0 = (float)(1.0 - frac);
                float h = w0 * emb[(size_t)sk[i0] * CC + c]
                        + w1 * emb[(size_t)sk[i1] * CC + c];
                size_t off = ((size_t)b * NN + n) * CC + c;
                float prev = (pn == 1) ? f[off] : f_rest[off];
                float fre = prev - h;
                f_rest[off] = fre;
                fr[n] = fre;
                acc_sq += fre * fre;
                if (pn == NN) out[off] = f[off] - fre;
            }
            int wv = tid >> 6, ln = tid & 63;
            #pragma unroll
            for (int m = 32; m >= 1; m >>= 1) acc_sq += __shfl_xor(acc_sq, m, 64);
            if (ln == 0) red[wv] = acc_sq;
            if (pn < NN) {
                int pn2 = pn + 1;
                for (int p = 0; p < pn2; ++p) {
                    int s = (p * NN) / pn2;
                    int e = ((p + 1) * NN + pn2 - 1) / pn2;
                    float v = 0.f;
                    for (int n = s; n < e; ++n) v += fr[n];
                    v *= 1.0f / (float)(e - s);
                    rest8[((size_t)(b * pn2 + p)) * CC + c] = f2fp8(4.0f * v);
                }
            }
            __syncthreads();
            if (tid == 0)
                atomicAdd(&slots[b & 255], (red[0] + red[1]) + (red[2] + red[3]));
        }
        grid.sync();
    }

    // ---------------- final ----------------
    if (bid == 0) {
        float v = slots[tid];
        #pragma unroll
        for (int m = 32; m >= 1; m >>= 1) v += __shfl_xor(v, m, 64);
        float* red = (float*)smem;
        int wv = tid >> 6, ln = tid & 63;
        if (ln == 0) red[wv] = v;
        __syncthreads();
        if (tid == 0) {
            float S = (red[0] + red[1]) + (red[2] + red[3]);
            float qlat = S / (float)BNC / (float)NN;
            out[BNC]     = 0.25f * qlat;   // commit
            out[BNC + 1] = qlat;           // qlat
        }
    }
}

// ---------------------------------------------------------------------------
extern "C" void kernel_launch(void* const* d_in, const int* in_sizes, int n_in,
                              void* d_out, int out_size, void* d_ws, size_t ws_size,
                              hipStream_t stream) {
    (void)in_sizes; (void)n_in; (void)out_size; (void)ws_size;
    const float* f   = (const float*)d_in[0];   // [B, N, C]
    const float* emb = (const float*)d_in[1];   // [K, C]
    float* out = (float*)d_out;                 // f_hat [B*N*C] + 2 scalars

    float* ws     = (float*)d_ws;
    float* f_rest = ws;                                    // BNC floats
    float* slots  = f_rest + BNC;                          // 256
    u64* packed_all = (u64*)(slots + 256);                 // 512*136
    u8* rest8 = (u8*)(packed_all + (size_t)BB * 136);      // 8192*256 fp8
    u8* emb8  = rest8 + (size_t)BB * NN * CC;              // 8192*256 fp8

    int occ = 0;
    hipOccupancyMaxActiveBlocksPerMultiprocessor(&occ, (const void*)vq_kernel,
                                                 256, 0);
    if (occ < 1) occ = 1;
    int nb = occ * 256;            // 256 CUs
    if (nb > 512) nb = 512;

    void* args[] = {(void*)&f, (void*)&emb, (void*)&f_rest, (void*)&rest8,
                    (void*)&emb8, (void*)&packed_all, (void*)&slots, (void*)&out};
    hipLaunchCooperativeKernel((const void*)vq_kernel, dim3(nb), dim3(256),
                               args, 0, stream);
}

// Round 9
// 1501.041 us; speedup vs baseline: 1.0804x; 1.0804x over previous
//
#include <hip/hip_runtime.h>
#include <math.h>

#define BB 512
#define NN 16
#define CC 256
#define KK 8192
#define BNC (BB*NN*CC)

typedef unsigned char u8;
typedef unsigned long long u64;
typedef __attribute__((ext_vector_type(8))) int i32x8;
typedef __attribute__((ext_vector_type(4))) float f32x4;

#define SCALE_A 0x7D7D7D7D   // e8m0 125 -> 2^-2  (rest stored x4)
#define SCALE_B 0x73737373   // e8m0 115 -> 2^-12 (emb stored x4096)

__device__ __forceinline__ void gl2lds16(const void* g, void* l) {
    __builtin_amdgcn_global_load_lds(
        (const __attribute__((address_space(1))) void*)g,
        (__attribute__((address_space(3))) void*)l, 16, 0, 0);
}
__device__ __forceinline__ u64 shfl_xor_u64(u64 v, int m) {
    unsigned lo = (unsigned)v, hi = (unsigned)(v >> 32);
    lo = __shfl_xor(lo, m, 64);
    hi = __shfl_xor(hi, m, 64);
    return ((u64)hi << 32) | lo;
}

// ---------------------------------------------------------------------------
__global__ void cvt_emb_kernel(const float* __restrict__ emb, u8* __restrict__ out) {
    int gid = blockIdx.x * blockDim.x + threadIdx.x;
    float4 v = ((const float4*)emb)[gid];
    int p = __builtin_amdgcn_cvt_pk_fp8_f32(v.x*4096.f, v.y*4096.f, 0, false);
    p = __builtin_amdgcn_cvt_pk_fp8_f32(v.z*4096.f, v.w*4096.f, p, true);
    ((int*)out)[gid] = p;
}

// ---------------------------------------------------------------------------
// step_kernel(pn): phase 1 = update(pn-1) fused (reads fr_in/packed_prev,
// writes fr_out + qlat partials from y==0 owner blocks) + pool -> fp8 A-tile
// built directly in LDS. phase 2 = fp8-MX dist for pn (B wave-private
// double-buffered via global_load_lds, vmcnt(8) discipline, zero barriers in
// the K-loop; A-frags hoisted to VGPRs once).
__global__ __launch_bounds__(256, 2) void step_kernel(
        const float* __restrict__ f, const float* __restrict__ emb,
        const u8* __restrict__ emb8,
        const float* __restrict__ fr_in, float* __restrict__ fr_out,
        const u64* __restrict__ packed_prev, u64* __restrict__ packed_cur,
        float* __restrict__ slots, int pn, int cpb) {
    __shared__ __align__(16) u8 smem[81920];   // 16 KB A | 64 KB B-ring
    u8* sA = smem;
    u8* sB = smem + 16384;
    const int tid = threadIdx.x;
    const int w = tid >> 6, l = tid & 63;
    const int ccol = l & 15, quad = l >> 4;
    const int r0 = blockIdx.x * 64;
    const int c0 = blockIdx.y * cpb;
    const int sg = ((l & 7) - (l >> 3)) & 7;

    // ---- prefetch B chunks 0,1 now; the pre-dist barrier drains them ----
    {
        const u8* b0 = emb8 + (size_t)(c0 + w * 64) * CC;
        #pragma unroll
        for (int o = 0; o < 8; ++o)
            gl2lds16(b0 + (size_t)(o*8 + (l>>3)) * CC + sg*16,
                     sB + w*16384 + o*1024);
        #pragma unroll
        for (int o = 0; o < 8; ++o)
            gl2lds16(b0 + (size_t)(o*8 + (l>>3)) * CC + 128 + sg*16,
                     sB + w*16384 + 8192 + o*1024);
    }

    // ---- phase 1: build A (update(pn-1) + pool), layout slot(r,g)=r*256+((g+r)&15)*16
    const int c4 = l * 4;
    const bool writer = (blockIdx.y == 0);
    if (pn == 1) {
        for (int bb = w; bb < 64; bb += 4) {
            int b = r0 + bb;
            const float* fb = f + (size_t)b * NN * CC + c4;
            float4 s = {0.f, 0.f, 0.f, 0.f};
            #pragma unroll
            for (int n = 0; n < NN; ++n) {
                float4 x = *(const float4*)(fb + n * CC);
                s.x += x.x; s.y += x.y; s.z += x.z; s.w += x.w;
            }
            int pk = __builtin_amdgcn_cvt_pk_fp8_f32(s.x*0.25f, s.y*0.25f, 0, false);
            pk = __builtin_amdgcn_cvt_pk_fp8_f32(s.z*0.25f, s.w*0.25f, pk, true);
            *(int*)(sA + bb*256 + ((((l>>2) + bb) & 15) << 4) + (l & 3)*4) = pk;
        }
    } else {
        const int pnm1 = pn - 1;
        const int b_first = r0 / pn, b_last = (r0 + 63) / pn;
        for (int bb = w; bb <= b_last - b_first; bb += 4) {
            const int b = b_first + bb;
            const float* fin = ((pn == 2) ? f : fr_in) + (size_t)b * NN * CC + c4;
            const u64* pp = packed_prev + (size_t)b * pnm1;
            if (writer) {
                float accq = 0.f;
                float* fo = fr_out + (size_t)b * NN * CC + c4;
                #pragma unroll
                for (int n = 0; n < NN; ++n) {
                    double pos = (n + 0.5) * ((double)pnm1 / 16.0) - 0.5;
                    if (pos < 0.0) pos = 0.0;
                    int i0 = (int)pos; if (i0 > pnm1 - 1) i0 = pnm1 - 1;
                    int i1 = i0 + 1;   if (i1 > pnm1 - 1) i1 = pnm1 - 1;
                    double frac = pos - (double)i0;
                    float w1f = (float)frac, w0f = (float)(1.0 - frac);
                    int k0 = (int)(unsigned)(pp[i0] & 0xffffffffull);
                    int k1 = (int)(unsigned)(pp[i1] & 0xffffffffull);
                    float4 e0 = *(const float4*)(emb + (size_t)k0 * CC + c4);
                    float4 e1 = *(const float4*)(emb + (size_t)k1 * CC + c4);
                    float4 x = *(const float4*)(fin + n * CC);
                    float4 fe;
                    fe.x = x.x - (w0f*e0.x + w1f*e1.x);
                    fe.y = x.y - (w0f*e0.y + w1f*e1.y);
                    fe.z = x.z - (w0f*e0.z + w1f*e1.z);
                    fe.w = x.w - (w0f*e0.w + w1f*e1.w);
                    *(float4*)(fo + n * CC) = fe;
                    accq += fe.x*fe.x + fe.y*fe.y + fe.z*fe.z + fe.w*fe.w;
                }
                #pragma unroll
                for (int m = 32; m >= 1; m >>= 1) accq += __shfl_xor(accq, m, 64);
                if (l == 0 && b * pn >= r0) atomicAdd(&slots[b & 255], accq);
            }
            // pooling (all blocks; recompute fre per window element)
            for (int p = 0; p < pn; ++p) {
                int lrow = b * pn + p - r0;
                if (lrow < 0 || lrow >= 64) continue;
                int s_ = (p * NN) / pn;
                int e_ = ((p + 1) * NN + pn - 1) / pn;
                float4 v = {0.f, 0.f, 0.f, 0.f};
                for (int n = s_; n < e_; ++n) {
                    double pos = (n + 0.5) * ((double)pnm1 / 16.0) - 0.5;
                    if (pos < 0.0) pos = 0.0;
                    int i0 = (int)pos; if (i0 > pnm1 - 1) i0 = pnm1 - 1;
                    int i1 = i0 + 1;   if (i1 > pnm1 - 1) i1 = pnm1 - 1;
                    double frac = pos - (double)i0;
                    float w1f = (float)frac, w0f = (float)(1.0 - frac);
                    int k0 = (int)(unsigned)(pp[i0] & 0xffffffffull);
                    int k1 = (int)(unsigned)(pp[i1] & 0xffffffffull);
                    float4 e0 = *(const float4*)(emb + (size_t)k0 * CC + c4);
                    float4 e1 = *(const float4*)(emb + (size_t)k1 * CC + c4);
                    float4 x = *(const float4*)(fin + n * CC);
                    v.x += x.x - (w0f*e0.x + w1f*e1.x);
                    v.y += x.y - (w0f*e0.y + w1f*e1.y);
                    v.z += x.z - (w0f*e0.z + w1f*e1.z);
                    v.w += x.w - (w0f*e0.w + w1f*e1.w);
                }
                float sc = 4.0f / (float)(e_ - s_);
                int pk = __builtin_amdgcn_cvt_pk_fp8_f32(v.x*sc, v.y*sc, 0, false);
                pk = __builtin_amdgcn_cvt_pk_fp8_f32(v.z*sc, v.w*sc, pk, true);
                *(int*)(sA + lrow*256 + ((((l>>2) + lrow) & 15) << 4) + (l & 3)*4) = pk;
            }
        }
    }
    __syncthreads();   // drains phase-1 vm traffic AND the B prefetch; A visible

    // ---- phase 2: dist ----
    const int ncb = cpb >> 8, nci = ncb * 2;

    // hoist A fragments once (reused across all cb)
    i32x8 afr[2][4];
    #pragma unroll
    for (int ki = 0; ki < 2; ++ki)
        #pragma unroll
        for (int tt = 0; tt < 4; ++tt) {
            int r = tt * 16 + ccol;
            int g0 = ki * 8 + quad * 2;
            int4 lo = *(const int4*)(sA + r * 256 + (((g0 + r) & 15) << 4));
            int4 hi = *(const int4*)(sA + r * 256 + (((g0 + 1 + r) & 15) << 4));
            i32x8 v;
            v[0]=lo.x; v[1]=lo.y; v[2]=lo.z; v[3]=lo.w;
            v[4]=hi.x; v[5]=hi.y; v[6]=hi.z; v[7]=hi.w;
            afr[ki][tt] = v;
        }

    float best[16];
    #pragma unroll
    for (int q = 0; q < 16; ++q) best[q] = 1e30f;
    f32x4 acc[4][4];

    for (int ci = 0; ci < nci; ++ci) {
        const int cb = ci >> 1, ki = ci & 1;
        if (ci == nci - 1) __builtin_amdgcn_s_waitcnt(0x0F70); // vmcnt(0)
        else               __builtin_amdgcn_s_waitcnt(0x0F78); // vmcnt(8)

        const u8* wb = sB + w * 16384 + ki * 8192;
        i32x8 bfr[4];
        #pragma unroll
        for (int j = 0; j < 4; ++j) {
            int c = j * 16 + ccol;
            int g0 = quad * 2;
            int4 lo = *(const int4*)(wb + c * 128 + (((g0 + c) & 7) << 4));
            int4 hi = *(const int4*)(wb + c * 128 + (((g0 + 1 + c) & 7) << 4));
            i32x8 v;
            v[0]=lo.x; v[1]=lo.y; v[2]=lo.z; v[3]=lo.w;
            v[4]=hi.x; v[5]=hi.y; v[6]=hi.z; v[7]=hi.w;
            bfr[j] = v;
        }
        if (ki == 0) {
            const f32x4 z = {0.f, 0.f, 0.f, 0.f};
            #pragma unroll
            for (int tt = 0; tt < 4; ++tt)
                #pragma unroll
                for (int j = 0; j < 4; ++j) acc[tt][j] = z;
        }
        #pragma unroll
        for (int tt = 0; tt < 4; ++tt)
            #pragma unroll
            for (int j = 0; j < 4; ++j)
                acc[tt][j] = __builtin_amdgcn_mfma_scale_f32_16x16x128_f8f6f4(
                                afr[ki][tt], bfr[j], acc[tt][j],
                                0, 0, 0, SCALE_A, 0, SCALE_B);
        if (ci + 2 < nci) {
            const int cb2 = (ci + 2) >> 1, ki2 = (ci + 2) & 1;
            const u8* b2 = emb8 + (size_t)(c0 + cb2 * 256 + w * 64) * CC + ki2 * 128;
            #pragma unroll
            for (int o = 0; o < 8; ++o)
                gl2lds16(b2 + (size_t)(o*8 + (l>>3)) * CC + sg * 16,
                         sB + w * 16384 + ki2 * 8192 + o * 1024);
        }
        if (ki == 1) {
            #pragma unroll
            for (int tt = 0; tt < 4; ++tt)
                #pragma unroll
                for (int r = 0; r < 4; ++r) {
                    const int slot = tt * 4 + r;
                    #pragma unroll
                    for (int j = 0; j < 4; ++j) {
                        float nd = -acc[tt][j][r];
                        unsigned u_ = (__float_as_uint(nd) & 0xFFFFFF80u)
                                      | (unsigned)((cb << 2) | j);
                        best[slot] = fminf(best[slot], __uint_as_float(u_));
                    }
                }
        }
    }

    // epilogue: reconstruct k, merge 16 ccol-lanes per quad, one atomicMin/row
    #pragma unroll
    for (int tt = 0; tt < 4; ++tt)
        #pragma unroll
        for (int r = 0; r < 4; ++r) {
            unsigned u_ = __float_as_uint(best[tt * 4 + r]);
            int idx = u_ & 0x7F;
            int k = c0 + (idx >> 2) * 256 + w * 64 + (idx & 3) * 16 + ccol;
            int sgn = ((int)u_) >> 31;
            unsigned ordu = u_ ^ ((unsigned)sgn | 0x80000000u);
            u64 p = ((u64)ordu << 32) | (unsigned)k;
            #pragma unroll
            for (int m = 1; m < 16; m <<= 1) {
                u64 o = shfl_xor_u64(p, m);
                if (o < p) p = o;
            }
            if (ccol == 0)
                atomicMin(&packed_cur[r0 + tt * 16 + quad * 4 + r], p);
        }
}

// ---------------------------------------------------------------------------
// update(16): pn=16 upsample is identity (pos=n, frac=0). Writes out = f_hat.
__global__ void final_update_kernel(const float* __restrict__ f,
                                    const float* __restrict__ emb,
                                    const float* __restrict__ fr_in,
                                    const u64* __restrict__ packed,
                                    float* __restrict__ slots,
                                    float* __restrict__ out) {
    int b = blockIdx.x, c = threadIdx.x;
    __shared__ int sk[NN];
    __shared__ float red[4];
    if (c < NN) sk[c] = (int)(unsigned)(packed[b * NN + c] & 0xffffffffull);
    __syncthreads();
    float accq = 0.f;
    #pragma unroll
    for (int n = 0; n < NN; ++n) {
        float h = emb[(size_t)sk[n] * CC + c];
        size_t off = ((size_t)b * NN + n) * CC + c;
        float fre = fr_in[off] - h;
        out[off] = f[off] - fre;
        accq += fre * fre;
    }
    int wv = c >> 6, ln = c & 63;
    #pragma unroll
    for (int m = 32; m >= 1; m >>= 1) accq += __shfl_xor(accq, m, 64);
    if (ln == 0) red[wv] = accq;
    __syncthreads();
    if (c == 0)
        atomicAdd(&slots[b & 255], (red[0] + red[1]) + (red[2] + red[3]));
}

// ---------------------------------------------------------------------------
__global__ void final_kernel(const float* __restrict__ slots, float* __restrict__ out_scalars) {
    float v = slots[threadIdx.x];
    #pragma unroll
    for (int m = 32; m >= 1; m >>= 1) v += __shfl_xor(v, m, 64);
    __shared__ float red[4];
    int wv = threadIdx.x >> 6, ln = threadIdx.x & 63;
    if (ln == 0) red[wv] = v;
    __syncthreads();
    if (threadIdx.x == 0) {
        float S = (red[0] + red[1]) + (red[2] + red[3]);
        float qlat = S / (float)BNC / (float)NN;
        out_scalars[0] = 0.25f * qlat;   // commit
        out_scalars[1] = qlat;           // qlat
    }
}

// ---------------------------------------------------------------------------
extern "C" void kernel_launch(void* const* d_in, const int* in_sizes, int n_in,
                              void* d_out, int out_size, void* d_ws, size_t ws_size,
                              hipStream_t stream) {
    (void)in_sizes; (void)n_in; (void)out_size; (void)ws_size;
    const float* f   = (const float*)d_in[0];   // [B, N, C]
    const float* emb = (const float*)d_in[1];   // [K, C]
    float* out = (float*)d_out;                 // f_hat [B*N*C] + 2 scalars

    float* ws = (float*)d_ws;
    float* frb[2];
    frb[0] = ws;                                // BNC
    frb[1] = frb[0] + BNC;                      // BNC
    float* slots = frb[1] + BNC;                // 256
    u64* packed_all = (u64*)(slots + 256);      // 512*136
    u8* emb8 = (u8*)(packed_all + (size_t)BB * 136);   // 8192*256 fp8

    hipMemsetAsync(slots, 0, 256 * sizeof(float), stream);
    hipMemsetAsync(packed_all, 0xFF, (size_t)BB * 136 * sizeof(u64), stream);
    cvt_emb_kernel<<<KK * CC / 4 / 256, 256, 0, stream>>>(emb, emb8);

    // codebook splits per pn: ncb = (KK/splits)/256 <= 8 (fold index fits 7 bits)
    static const int splits_tab[17] = {0,32,32,16,16,8,8,8,8,4,4,4,4,4,4,4,4};

    for (int pn = 1; pn <= NN; ++pn) {
        int splits = splits_tab[pn];
        int cpb = KK / splits;
        u64* packed_cur  = packed_all + (size_t)BB * (pn * (pn - 1) / 2);
        u64* packed_prev = (pn >= 2)
            ? packed_all + (size_t)BB * ((pn - 1) * (pn - 2) / 2) : packed_all;
        float* fr_out = frb[(pn - 1) & 1];
        const float* fr_in = frb[(pn - 2) & 1];   // unused for pn<=2
        dim3 grid(8 * pn, splits);
        step_kernel<<<grid, 256, 0, stream>>>(f, emb, emb8, fr_in, fr_out,
                                              packed_prev, packed_cur,
                                              slots, pn, cpb);
    }
    final_update_kernel<<<BB, 256, 0, stream>>>(f, emb, frb[1],
                                                packed_all + (size_t)BB * 120,
                                                slots, out);
    final_kernel<<<1, 256, 0, stream>>>(slots, out + BNC);
}